// Round 6
// baseline (111.136 us; speedup 1.0000x reference)
//
#include <hip/hip_runtime.h>

typedef __attribute__((ext_vector_type(8))) short bf16x8;
typedef __attribute__((ext_vector_type(4))) float f32x4;
typedef __attribute__((ext_vector_type(2))) unsigned int u32x2;
typedef __attribute__((ext_vector_type(4))) unsigned int u32x4;

__device__ __forceinline__ unsigned short f2bf(float f) {
  return __builtin_bit_cast(unsigned short, (__bf16)f);
}
__device__ __forceinline__ unsigned pk2(float a, float b) {
  return (unsigned)f2bf(a) | ((unsigned)f2bf(b) << 16);
}
__device__ __forceinline__ bf16x8 frag(u32x4 v) { return __builtin_bit_cast(bf16x8, v); }

// wave-level compiler memory fence (cross-lane LDS handoff within a wave)
__device__ __forceinline__ void wfence() {
  asm volatile("" ::: "memory");
  __builtin_amdgcn_wave_barrier();
}

#define MFMA16(a, b, c) __builtin_amdgcn_mfma_f32_16x16x32_bf16(a, b, c, 0, 0, 0)

#define LR 72            // 64-col rows, 144 B stride: 16B-aligned, bank-rotating
#define OFF_VT 4608      // K rows at 0; VT rows at 4608; Q (-> attn) rows at 9216
#define OFF_Q  9216
#define ZOK 64           // 16B zero block in K row-0 padding
#define LDS_TOT 13824    // ushorts = 27,648 B -> 5 blocks/CU

// ---- weight prep (identical to R5 -- numerically validated) ----
// pi k-permutation: slot(ks,g,j) -> source col 16*(2ks + (j>>2)) + 4g + (j&3).
// chunks (1 KB each): [0,8)=WqT(pi, x0.125*log2e) [8,16)=WkT(pi) [16,24)=Wv(pi)
// [24,32)=WpT(natural) [32,64)=W1T(pi) [64,96)=W2T(pi per 64-chunk)
__global__ void prep_weights(const float* __restrict__ wq, const float* __restrict__ wk,
                             const float* __restrict__ wv, const float* __restrict__ projw,
                             const float* __restrict__ fc1w, const float* __restrict__ fc2w,
                             unsigned short* __restrict__ ws) {
  int c = blockIdx.x, l = threadIdx.x;
  int g = l >> 4, jl = l & 15;
  int kind, T, ks;
  if (c < 8)       { kind = 0; T = c >> 1;        ks = c & 1; }
  else if (c < 16) { kind = 1; T = (c - 8) >> 1;  ks = (c - 8) & 1; }
  else if (c < 24) { kind = 2; T = (c - 16) >> 1; ks = (c - 16) & 1; }
  else if (c < 32) { kind = 3; T = (c - 24) >> 1; ks = (c - 24) & 1; }
  else if (c < 64) { kind = 4; T = (c - 32) >> 1; ks = (c - 32) & 1; }
  else             { kind = 5; T = (c - 64) >> 3; ks = (c - 64) & 7; }
  int n = 16 * T + jl;
  unsigned short* dst = ws + c * 512 + l * 8;
  #pragma unroll
  for (int jj = 0; jj < 8; ++jj) {
    int kp = 16 * (2 * (ks & 1) + (jj >> 2)) + 4 * g + (jj & 3);   // pi slot->col
    int kn = 32 * ks + 8 * g + jj;                                  // natural
    float v;
    if (kind == 0)      v = wq[(n >> 3) * 512 + kp * 8 + (n & 7)] * 0.18033688011f;
    else if (kind == 1) v = wk[(n >> 3) * 512 + kp * 8 + (n & 7)];
    else if (kind == 2) v = wv[(n >> 3) * 512 + kp * 8 + (n & 7)];
    else if (kind == 3) v = projw[kn * 64 + n];
    else if (kind == 4) v = fc1w[kp * 256 + n];
    else                v = fc2w[(64 * (ks >> 1) + kp) * 64 + n];
    dst[jj] = f2bf(v);
  }
}

__global__ __launch_bounds__(256, 5) void block_fused(
    const float* __restrict__ x,
    const float* __restrict__ ln1w, const float* __restrict__ ln1b,
    const float* __restrict__ projb,
    const float* __restrict__ ln2w, const float* __restrict__ ln2b,
    const float* __restrict__ fc1b, const float* __restrict__ fc2b,
    const unsigned short* __restrict__ wsm, float* __restrict__ out) {
  __shared__ __attribute__((aligned(16))) unsigned short lds[LDS_TOT];

  const int tid  = threadIdx.x;
  const int w    = tid >> 6;     // wave 0..3 owns tokens 16w..16w+15
  const int lane = tid & 63;
  const int g    = lane >> 4;
  const int jl   = lane & 15;
  const size_t b = blockIdx.x;
  const float* xb = x + b * 4096;
  const f32x4 zf = {0.f, 0.f, 0.f, 0.f};

  const int myrow = 16 * w + jl;                 // this lane's token
  const int krow  = myrow * LR;                  // K region row
  const int qrow  = OFF_Q + myrow * LR;          // Q (-> attn) region row
  const int sigb  = 32 * (w >> 1) + 8 * g + 4 * (w & 1);  // sigma slot base for V

  // ---------- LN1 fully in registers (x loaded, consumed, discarded) ----------
  float mean, rstd;
  unsigned hr[8];
  {
    f32x4 xw[4];
    float s = 0.f, ss = 0.f;
    #pragma unroll
    for (int mi = 0; mi < 4; ++mi) {
      xw[mi] = *(const f32x4*)(xb + myrow * 64 + 16 * mi + 4 * g);
      #pragma unroll
      for (int r = 0; r < 4; ++r) { s += xw[mi][r]; ss += xw[mi][r] * xw[mi][r]; }
    }
    s  += __shfl_xor(s, 16, 64);  s  += __shfl_xor(s, 32, 64);
    ss += __shfl_xor(ss, 16, 64); ss += __shfl_xor(ss, 32, 64);
    mean = s * 0.015625f;
    rstd = rsqrtf(ss * 0.015625f - mean * mean + 1e-5f);
    #pragma unroll
    for (int mi = 0; mi < 4; ++mi) {
      f32x4 lw = *(const f32x4*)(ln1w + 16 * mi + 4 * g);
      f32x4 lb = *(const f32x4*)(ln1b + 16 * mi + 4 * g);
      float o0 = (xw[mi][0] - mean) * rstd * lw[0] + lb[0];
      float o1 = (xw[mi][1] - mean) * rstd * lw[1] + lb[1];
      float o2 = (xw[mi][2] - mean) * rstd * lw[2] + lb[2];
      float o3 = (xw[mi][3] - mean) * rstd * lw[3] + lb[3];
      hr[2 * mi] = pk2(o0, o1); hr[2 * mi + 1] = pk2(o2, o3);
    }
  }
  bf16x8 hb0 = frag((u32x4){hr[0], hr[1], hr[2], hr[3]});   // pi-layout B-frag ks=0
  bf16x8 hb1 = frag((u32x4){hr[4], hr[5], hr[6], hr[7]});   // ks=1

  // ---------- QKV: Q->LDS (natural rows), K->LDS, V->LDS VT (sigma slots) ----------
  #pragma unroll
  for (int mt = 0; mt < 4; ++mt) {
    bf16x8 aq0 = *(const bf16x8*)(wsm + (0 + 2 * mt) * 512 + lane * 8);
    bf16x8 aq1 = *(const bf16x8*)(wsm + (1 + 2 * mt) * 512 + lane * 8);
    f32x4 q = MFMA16(aq0, hb0, zf); q = MFMA16(aq1, hb1, q);
    *(u32x2*)(lds + qrow + 16 * mt + 4 * g) = (u32x2){pk2(q[0], q[1]), pk2(q[2], q[3])};

    bf16x8 ak0 = *(const bf16x8*)(wsm + (8 + 2 * mt) * 512 + lane * 8);
    bf16x8 ak1 = *(const bf16x8*)(wsm + (9 + 2 * mt) * 512 + lane * 8);
    f32x4 kk = MFMA16(ak0, hb0, zf); kk = MFMA16(ak1, hb1, kk);
    *(u32x2*)(lds + krow + 16 * mt + 4 * g) = (u32x2){pk2(kk[0], kk[1]), pk2(kk[2], kk[3])};

    // V non-swapped: lane holds V[16w+4g+r][16mt+jl] -> VT row 16mt+jl, sigma slot
    bf16x8 bv0 = *(const bf16x8*)(wsm + (16 + 2 * mt) * 512 + lane * 8);
    bf16x8 bv1 = *(const bf16x8*)(wsm + (17 + 2 * mt) * 512 + lane * 8);
    f32x4 vv = MFMA16(hb0, bv0, zf); vv = MFMA16(hb1, bv1, vv);
    *(u32x2*)(lds + OFF_VT + (16 * mt + jl) * LR + sigb) =
        (u32x2){pk2(vv[0], vv[1]), pk2(vv[2], vv[3])};
  }
  if (tid == 0) *(u32x4*)(lds + ZOK) = (u32x4){0u, 0u, 0u, 0u};
  __syncthreads();   // the ONLY barrier: publish K, VT (Q rows are wave-private)

  // ---------- attention: S^T=mfma(K,Q); lane-local softmax; PV; per-head dump ----------
  // head h reads Q cols [8h,8h+8) then overwrites them with attn cols [8h,8h+8):
  // all cross-head slices disjoint; same-head order forced by the register chain.
  #pragma unroll
  for (int h = 0; h < 8; ++h) {
    bf16x8 bq = *(const bf16x8*)(lds + ((g == 0) ? (qrow + 8 * h) : ZOK));
    unsigned Up[8];
    float sum = 0.f;
    #pragma unroll
    for (int mi = 0; mi < 4; ++mi) {
      if (mi <= w) {   // wave-uniform causal tile skip
        bf16x8 ak = *(const bf16x8*)(lds + ((g == 0) ? ((16 * mi + jl) * LR + 8 * h) : ZOK));
        f32x4 sc = MFMA16(ak, bq, zf);
        float e0 = exp2f(sc[0]), e1 = exp2f(sc[1]);
        float e2 = exp2f(sc[2]), e3 = exp2f(sc[3]);
        if (mi == w) {   // diagonal: keep s<=q  <=>  4g+r <= jl
          e0 = (4 * g + 0 <= jl) ? e0 : 0.f;
          e1 = (4 * g + 1 <= jl) ? e1 : 0.f;
          e2 = (4 * g + 2 <= jl) ? e2 : 0.f;
          e3 = (4 * g + 3 <= jl) ? e3 : 0.f;
        }
        sum += (e0 + e1) + (e2 + e3);
        Up[2 * mi] = pk2(e0, e1); Up[2 * mi + 1] = pk2(e2, e3);
      } else { Up[2 * mi] = 0u; Up[2 * mi + 1] = 0u; }
    }
    sum += __shfl_xor(sum, 16, 64);
    sum += __shfl_xor(sum, 32, 64);
    float inv = __builtin_amdgcn_rcpf(sum);
    bf16x8 bp0 = frag((u32x4){Up[0], Up[1], Up[2], Up[3]});   // pi-slots = sigma tokens
    bf16x8 bp1 = frag((u32x4){Up[4], Up[5], Up[6], Up[7]});
    const int vtr = OFF_VT + (8 * h + jl) * LR;
    bf16x8 aw0 = *(const bf16x8*)(lds + ((jl < 8) ? (vtr + 8 * g) : ZOK));
    bf16x8 aw1 = *(const bf16x8*)(lds + ((jl < 8) ? (vtr + 32 + 8 * g) : ZOK));
    f32x4 pv = MFMA16(aw0, bp0, zf); pv = MFMA16(aw1, bp1, pv);
    if (g < 2)   // attn[myrow][8h+4g+{0..3}] -> dead Q slice of own row
      *(u32x2*)(lds + qrow + 8 * h + 4 * g) =
          (u32x2){pk2(pv[0] * inv, pv[1] * inv), pk2(pv[2] * inv, pv[3] * inv)};
  }
  wfence();   // predicated (g<2) attn stores -> all-lane bat reads (cross-lane)
  bf16x8 bat0 = *(const bf16x8*)(lds + qrow + 8 * g);
  bf16x8 bat1 = *(const bf16x8*)(lds + qrow + 32 + 8 * g);

  // ---------- proj (swapped, natural k) + residual; x re-read (L2-hot) ----------
  f32x4 x2[4];
  #pragma unroll
  for (int mi = 0; mi < 4; ++mi) {
    bf16x8 a0 = *(const bf16x8*)(wsm + (24 + 2 * mi) * 512 + lane * 8);
    bf16x8 a1 = *(const bf16x8*)(wsm + (25 + 2 * mi) * 512 + lane * 8);
    f32x4 acc = MFMA16(a0, bat0, zf); acc = MFMA16(a1, bat1, acc);
    f32x4 xv = *(const f32x4*)(xb + myrow * 64 + 16 * mi + 4 * g);
    f32x4 pb = *(const f32x4*)(projb + 16 * mi + 4 * g);
    x2[mi] = xv + acc + pb;
  }

  // ---------- LN2 in registers ----------
  float mean2, rstd2;
  {
    float s = 0.f, ss = 0.f;
    #pragma unroll
    for (int mi = 0; mi < 4; ++mi)
      #pragma unroll
      for (int r = 0; r < 4; ++r) { s += x2[mi][r]; ss += x2[mi][r] * x2[mi][r]; }
    s  += __shfl_xor(s, 16, 64);  s  += __shfl_xor(s, 32, 64);
    ss += __shfl_xor(ss, 16, 64); ss += __shfl_xor(ss, 32, 64);
    mean2 = s * 0.015625f;
    rstd2 = rsqrtf(ss * 0.015625f - mean2 * mean2 + 1e-5f);
  }
  unsigned h2[8];
  #pragma unroll
  for (int mi = 0; mi < 4; ++mi) {
    f32x4 lw = *(const f32x4*)(ln2w + 16 * mi + 4 * g);
    f32x4 lb = *(const f32x4*)(ln2b + 16 * mi + 4 * g);
    float o0 = (x2[mi][0] - mean2) * rstd2 * lw[0] + lb[0];
    float o1 = (x2[mi][1] - mean2) * rstd2 * lw[1] + lb[1];
    float o2 = (x2[mi][2] - mean2) * rstd2 * lw[2] + lb[2];
    float o3 = (x2[mi][3] - mean2) * rstd2 * lw[3] + lb[3];
    h2[2 * mi] = pk2(o0, o1); h2[2 * mi + 1] = pk2(o2, o3);
  }
  bf16x8 hc0 = frag((u32x4){h2[0], h2[1], h2[2], h2[3]});
  bf16x8 hc1 = frag((u32x4){h2[4], h2[5], h2[6], h2[7]});

  // ---------- FF: fc1 (pi) -> relu regs -> fc2 (pi per 64-chunk), all registers ----------
  f32x4 acc2[4];
  #pragma unroll
  for (int mi = 0; mi < 4; ++mi) acc2[mi] = zf;
  #pragma unroll
  for (int c = 0; c < 4; ++c) {
    unsigned fr[8];
    #pragma unroll
    for (int ml = 0; ml < 4; ++ml) {
      int T = 4 * c + ml;
      bf16x8 a0 = *(const bf16x8*)(wsm + (32 + 2 * T) * 512 + lane * 8);
      bf16x8 a1 = *(const bf16x8*)(wsm + (33 + 2 * T) * 512 + lane * 8);
      f32x4 acc = MFMA16(a0, hc0, zf); acc = MFMA16(a1, hc1, acc);
      f32x4 bb = *(const f32x4*)(fc1b + 16 * T + 4 * g);
      float r0 = fmaxf(acc[0] + bb[0], 0.f), r1 = fmaxf(acc[1] + bb[1], 0.f);
      float r2 = fmaxf(acc[2] + bb[2], 0.f), r3 = fmaxf(acc[3] + bb[3], 0.f);
      fr[2 * ml] = pk2(r0, r1); fr[2 * ml + 1] = pk2(r2, r3);
    }
    bf16x8 bf0 = frag((u32x4){fr[0], fr[1], fr[2], fr[3]});
    bf16x8 bf1 = frag((u32x4){fr[4], fr[5], fr[6], fr[7]});
    #pragma unroll
    for (int mi = 0; mi < 4; ++mi) {
      bf16x8 w20 = *(const bf16x8*)(wsm + (64 + 8 * mi + 2 * c) * 512 + lane * 8);
      bf16x8 w21 = *(const bf16x8*)(wsm + (65 + 8 * mi + 2 * c) * 512 + lane * 8);
      acc2[mi] = MFMA16(w20, bf0, acc2[mi]);
      acc2[mi] = MFMA16(w21, bf1, acc2[mi]);
    }
  }

  // ---------- epilogue ----------
  {
    float* ob = out + b * 4096 + myrow * 64;
    #pragma unroll
    for (int mi = 0; mi < 4; ++mi) {
      f32x4 fb = *(const f32x4*)(fc2b + 16 * mi + 4 * g);
      f32x4 o = x2[mi] + acc2[mi] + fb;
      *(f32x4*)(ob + 16 * mi + 4 * g) = o;
    }
  }
}

extern "C" void kernel_launch(void* const* d_in, const int* in_sizes, int n_in,
                              void* d_out, int out_size, void* d_ws, size_t ws_size,
                              hipStream_t stream) {
  const float* x     = (const float*)d_in[0];
  const float* ln1w  = (const float*)d_in[1];
  const float* ln1b  = (const float*)d_in[2];
  const float* wq    = (const float*)d_in[3];
  const float* wk    = (const float*)d_in[4];
  const float* wvp   = (const float*)d_in[5];
  const float* projw = (const float*)d_in[6];
  const float* projb = (const float*)d_in[7];
  const float* ln2w  = (const float*)d_in[8];
  const float* ln2b  = (const float*)d_in[9];
  const float* fc1w  = (const float*)d_in[10];
  const float* fc1b  = (const float*)d_in[11];
  const float* fc2w  = (const float*)d_in[12];
  const float* fc2b  = (const float*)d_in[13];
  unsigned short* ws = (unsigned short*)d_ws;   // 96 KB repacked weights
  float* out = (float*)d_out;

  prep_weights<<<dim3(96), dim3(64), 0, stream>>>(wq, wk, wvp, projw, fc1w, fc2w, ws);

  int nblk = in_sizes[0] / 4096;
  block_fused<<<dim3(nblk), dim3(256), 0, stream>>>(
      x, ln1w, ln1b, projb, ln2w, ln2b, fc1b, fc2b, ws, out);
}

// Round 7
// 103.289 us; speedup vs baseline: 1.0760x; 1.0760x over previous
//
#include <hip/hip_runtime.h>

typedef __attribute__((ext_vector_type(8))) short bf16x8;
typedef __attribute__((ext_vector_type(4))) float f32x4;
typedef __attribute__((ext_vector_type(2))) unsigned int u32x2;
typedef __attribute__((ext_vector_type(4))) unsigned int u32x4;

__device__ __forceinline__ unsigned short f2bf(float f) {
  return __builtin_bit_cast(unsigned short, (__bf16)f);
}
__device__ __forceinline__ unsigned pk2(float a, float b) {
  return (unsigned)f2bf(a) | ((unsigned)f2bf(b) << 16);
}
__device__ __forceinline__ bf16x8 frag(u32x4 v) { return __builtin_bit_cast(bf16x8, v); }

#if __has_builtin(__builtin_amdgcn_exp2f)
#define EXP2(x) __builtin_amdgcn_exp2f(x)
#else
#define EXP2(x) exp2f(x)
#endif

// wave-level compiler memory fence (cross-lane LDS handoff within a wave)
__device__ __forceinline__ void wfence() {
  asm volatile("" ::: "memory");
  __builtin_amdgcn_wave_barrier();
}

#define MFMA16(a, b, c) __builtin_amdgcn_mfma_f32_16x16x32_bf16(a, b, c, 0, 0, 0)

#define LR 72            // 64-col rows, 144 B stride: 16B-aligned, bank-rotating
#define OFF_VT 4608      // K rows at 0; VT rows at 4608; Q (-> attn) rows at 9216
#define OFF_Q  9216
#define ZOK 64           // 16B zero block in K row-0 padding
#define LDS_TOT 13824    // ushorts = 27,648 B -> 5 blocks/CU

// ---- weight prep (identical to R5/R6 -- numerically validated) ----
// pi k-permutation: slot(ks,g,j) -> source col 16*(2ks + (j>>2)) + 4g + (j&3).
// chunks (1 KB each): [0,8)=WqT(pi, x0.125*log2e) [8,16)=WkT(pi) [16,24)=Wv(pi)
// [24,32)=WpT(natural) [32,64)=W1T(pi) [64,96)=W2T(pi per 64-chunk)
__global__ void prep_weights(const float* __restrict__ wq, const float* __restrict__ wk,
                             const float* __restrict__ wv, const float* __restrict__ projw,
                             const float* __restrict__ fc1w, const float* __restrict__ fc2w,
                             unsigned short* __restrict__ ws) {
  int c = blockIdx.x, l = threadIdx.x;
  int g = l >> 4, jl = l & 15;
  int kind, T, ks;
  if (c < 8)       { kind = 0; T = c >> 1;        ks = c & 1; }
  else if (c < 16) { kind = 1; T = (c - 8) >> 1;  ks = (c - 8) & 1; }
  else if (c < 24) { kind = 2; T = (c - 16) >> 1; ks = (c - 16) & 1; }
  else if (c < 32) { kind = 3; T = (c - 24) >> 1; ks = (c - 24) & 1; }
  else if (c < 64) { kind = 4; T = (c - 32) >> 1; ks = (c - 32) & 1; }
  else             { kind = 5; T = (c - 64) >> 3; ks = (c - 64) & 7; }
  int n = 16 * T + jl;
  unsigned short* dst = ws + c * 512 + l * 8;
  #pragma unroll
  for (int jj = 0; jj < 8; ++jj) {
    int kp = 16 * (2 * (ks & 1) + (jj >> 2)) + 4 * g + (jj & 3);   // pi slot->col
    int kn = 32 * ks + 8 * g + jj;                                  // natural
    float v;
    if (kind == 0)      v = wq[(n >> 3) * 512 + kp * 8 + (n & 7)] * 0.18033688011f;
    else if (kind == 1) v = wk[(n >> 3) * 512 + kp * 8 + (n & 7)];
    else if (kind == 2) v = wv[(n >> 3) * 512 + kp * 8 + (n & 7)];
    else if (kind == 3) v = projw[kn * 64 + n];
    else if (kind == 4) v = fc1w[kp * 256 + n];
    else                v = fc2w[(64 * (ks >> 1) + kp) * 64 + n];
    dst[jj] = f2bf(v);
  }
}

__device__ __forceinline__ bf16x8 ldw(const unsigned short* __restrict__ wsm,
                                      int chunk, int lane) {
  return *(const bf16x8*)(wsm + chunk * 512 + lane * 8);
}

__global__ __launch_bounds__(256, 5) void block_fused(
    const float* __restrict__ x,
    const float* __restrict__ ln1w, const float* __restrict__ ln1b,
    const float* __restrict__ projb,
    const float* __restrict__ ln2w, const float* __restrict__ ln2b,
    const float* __restrict__ fc1b, const float* __restrict__ fc2b,
    const unsigned short* __restrict__ wsm, float* __restrict__ out) {
  __shared__ __attribute__((aligned(16))) unsigned short lds[LDS_TOT];

  const int tid  = threadIdx.x;
  const int w    = tid >> 6;     // wave 0..3 owns tokens 16w..16w+15
  const int lane = tid & 63;
  const int g    = lane >> 4;
  const int jl   = lane & 15;
  const size_t b = blockIdx.x;
  const float* xb = x + b * 4096;
  const f32x4 zf = {0.f, 0.f, 0.f, 0.f};

  const int myrow = 16 * w + jl;                 // this lane's token
  const int krow  = myrow * LR;                  // K region row
  const int qrow  = OFF_Q + myrow * LR;          // Q (-> attn) region row
  const int sigb  = 32 * (w >> 1) + 8 * g + 4 * (w & 1);  // sigma slot base for V

  // ---------- LN1 fully in registers; all loads issued up front ----------
  float mean, rstd;
  unsigned hr[8];
  {
    f32x4 xw[4], lw1[4], lb1[4];
    #pragma unroll
    for (int mi = 0; mi < 4; ++mi) {
      xw[mi]  = *(const f32x4*)(xb + myrow * 64 + 16 * mi + 4 * g);
      lw1[mi] = *(const f32x4*)(ln1w + 16 * mi + 4 * g);
      lb1[mi] = *(const f32x4*)(ln1b + 16 * mi + 4 * g);
    }
    float s = 0.f, ss = 0.f;
    #pragma unroll
    for (int mi = 0; mi < 4; ++mi)
      #pragma unroll
      for (int r = 0; r < 4; ++r) { s += xw[mi][r]; ss += xw[mi][r] * xw[mi][r]; }
    s  += __shfl_xor(s, 16, 64);  s  += __shfl_xor(s, 32, 64);
    ss += __shfl_xor(ss, 16, 64); ss += __shfl_xor(ss, 32, 64);
    mean = s * 0.015625f;
    rstd = rsqrtf(ss * 0.015625f - mean * mean + 1e-5f);
    #pragma unroll
    for (int mi = 0; mi < 4; ++mi) {
      float o0 = (xw[mi][0] - mean) * rstd * lw1[mi][0] + lb1[mi][0];
      float o1 = (xw[mi][1] - mean) * rstd * lw1[mi][1] + lb1[mi][1];
      float o2 = (xw[mi][2] - mean) * rstd * lw1[mi][2] + lb1[mi][2];
      float o3 = (xw[mi][3] - mean) * rstd * lw1[mi][3] + lb1[mi][3];
      hr[2 * mi] = pk2(o0, o1); hr[2 * mi + 1] = pk2(o2, o3);
    }
  }
  bf16x8 hb0 = frag((u32x4){hr[0], hr[1], hr[2], hr[3]});   // pi-layout B-frag ks=0
  bf16x8 hb1 = frag((u32x4){hr[4], hr[5], hr[6], hr[7]});   // ks=1

  // ---------- QKV with 2-deep rolling weight prefetch ----------
  {
    bf16x8 fq[2][2], fk[2][2], fv[2][2];
    fq[0][0] = ldw(wsm, 0, lane);  fq[0][1] = ldw(wsm, 1, lane);
    fk[0][0] = ldw(wsm, 8, lane);  fk[0][1] = ldw(wsm, 9, lane);
    fv[0][0] = ldw(wsm, 16, lane); fv[0][1] = ldw(wsm, 17, lane);
    #pragma unroll
    for (int mt = 0; mt < 4; ++mt) {
      const int cur = mt & 1, nxt = cur ^ 1;
      if (mt < 3) {   // issue next group while computing current
        fq[nxt][0] = ldw(wsm, 2 * mt + 2, lane);  fq[nxt][1] = ldw(wsm, 2 * mt + 3, lane);
        fk[nxt][0] = ldw(wsm, 10 + 2 * mt, lane); fk[nxt][1] = ldw(wsm, 11 + 2 * mt, lane);
        fv[nxt][0] = ldw(wsm, 18 + 2 * mt, lane); fv[nxt][1] = ldw(wsm, 19 + 2 * mt, lane);
      }
      f32x4 q = MFMA16(fq[cur][0], hb0, zf); q = MFMA16(fq[cur][1], hb1, q);
      *(u32x2*)(lds + qrow + 16 * mt + 4 * g) = (u32x2){pk2(q[0], q[1]), pk2(q[2], q[3])};

      f32x4 kk = MFMA16(fk[cur][0], hb0, zf); kk = MFMA16(fk[cur][1], hb1, kk);
      *(u32x2*)(lds + krow + 16 * mt + 4 * g) = (u32x2){pk2(kk[0], kk[1]), pk2(kk[2], kk[3])};

      // V non-swapped: lane holds V[16w+4g+r][16mt+jl] -> VT row 16mt+jl, sigma slot
      f32x4 vv = MFMA16(hb0, fv[cur][0], zf); vv = MFMA16(hb1, fv[cur][1], vv);
      *(u32x2*)(lds + OFF_VT + (16 * mt + jl) * LR + sigb) =
          (u32x2){pk2(vv[0], vv[1]), pk2(vv[2], vv[3])};
    }
  }
  if (tid == 0) *(u32x4*)(lds + ZOK) = (u32x4){0u, 0u, 0u, 0u};
  __syncthreads();   // the ONLY barrier: publish K, VT (Q rows are wave-private)

  // ---------- prefetch proj weights across the whole attention phase ----------
  bf16x8 wp[8];
  #pragma unroll
  for (int i = 0; i < 8; ++i) wp[i] = ldw(wsm, 24 + i, lane);

  // ---------- attention: S^T=mfma(K,Q); lane-local softmax; PV; per-head dump ----------
  #pragma unroll
  for (int h = 0; h < 8; ++h) {
    bf16x8 bq = *(const bf16x8*)(lds + ((g == 0) ? (qrow + 8 * h) : ZOK));
    unsigned Up[8];
    float sum = 0.f;
    #pragma unroll
    for (int mi = 0; mi < 4; ++mi) {
      if (mi <= w) {   // wave-uniform causal tile skip
        bf16x8 ak = *(const bf16x8*)(lds + ((g == 0) ? ((16 * mi + jl) * LR + 8 * h) : ZOK));
        f32x4 sc = MFMA16(ak, bq, zf);
        float e0 = EXP2(sc[0]), e1 = EXP2(sc[1]);
        float e2 = EXP2(sc[2]), e3 = EXP2(sc[3]);
        if (mi == w) {   // diagonal: keep s<=q  <=>  4g+r <= jl
          e0 = (4 * g + 0 <= jl) ? e0 : 0.f;
          e1 = (4 * g + 1 <= jl) ? e1 : 0.f;
          e2 = (4 * g + 2 <= jl) ? e2 : 0.f;
          e3 = (4 * g + 3 <= jl) ? e3 : 0.f;
        }
        sum += (e0 + e1) + (e2 + e3);
        Up[2 * mi] = pk2(e0, e1); Up[2 * mi + 1] = pk2(e2, e3);
      } else { Up[2 * mi] = 0u; Up[2 * mi + 1] = 0u; }
    }
    sum += __shfl_xor(sum, 16, 64);
    sum += __shfl_xor(sum, 32, 64);
    float inv = __builtin_amdgcn_rcpf(sum);
    bf16x8 bp0 = frag((u32x4){Up[0], Up[1], Up[2], Up[3]});   // pi-slots = sigma tokens
    bf16x8 bp1 = frag((u32x4){Up[4], Up[5], Up[6], Up[7]});
    const int vtr = OFF_VT + (8 * h + jl) * LR;
    bf16x8 aw0 = *(const bf16x8*)(lds + ((jl < 8) ? (vtr + 8 * g) : ZOK));
    bf16x8 aw1 = *(const bf16x8*)(lds + ((jl < 8) ? (vtr + 32 + 8 * g) : ZOK));
    f32x4 pv = MFMA16(aw0, bp0, zf); pv = MFMA16(aw1, bp1, pv);
    if (g < 2)   // attn[myrow][8h+4g+{0..3}] -> dead Q slice of own row
      *(u32x2*)(lds + qrow + 8 * h + 4 * g) =
          (u32x2){pk2(pv[0] * inv, pv[1] * inv), pk2(pv[2] * inv, pv[3] * inv)};
  }

  // issue residual x re-read + projb before the dump/bat round trip
  f32x4 xv[4], pbv[4];
  #pragma unroll
  for (int mi = 0; mi < 4; ++mi) {
    xv[mi]  = *(const f32x4*)(xb + myrow * 64 + 16 * mi + 4 * g);
    pbv[mi] = *(const f32x4*)(projb + 16 * mi + 4 * g);
  }
  wfence();   // predicated (g<2) attn stores -> all-lane bat reads (cross-lane)
  bf16x8 bat0 = *(const bf16x8*)(lds + qrow + 8 * g);
  bf16x8 bat1 = *(const bf16x8*)(lds + qrow + 32 + 8 * g);

  // LN2 scale prefetch (consumed after proj)
  f32x4 lw2[4], lb2[4];
  #pragma unroll
  for (int mi = 0; mi < 4; ++mi) {
    lw2[mi] = *(const f32x4*)(ln2w + 16 * mi + 4 * g);
    lb2[mi] = *(const f32x4*)(ln2b + 16 * mi + 4 * g);
  }

  // ---------- proj (swapped, natural k) + residual; x2 in fp32 regs ----------
  f32x4 x2[4];
  #pragma unroll
  for (int mi = 0; mi < 4; ++mi) {
    f32x4 acc = MFMA16(wp[2 * mi], bat0, zf); acc = MFMA16(wp[2 * mi + 1], bat1, acc);
    x2[mi] = xv[mi] + acc + pbv[mi];
  }

  // ---------- LN2 in registers ----------
  float mean2, rstd2;
  {
    float s = 0.f, ss = 0.f;
    #pragma unroll
    for (int mi = 0; mi < 4; ++mi)
      #pragma unroll
      for (int r = 0; r < 4; ++r) { s += x2[mi][r]; ss += x2[mi][r] * x2[mi][r]; }
    s  += __shfl_xor(s, 16, 64);  s  += __shfl_xor(s, 32, 64);
    ss += __shfl_xor(ss, 16, 64); ss += __shfl_xor(ss, 32, 64);
    mean2 = s * 0.015625f;
    rstd2 = rsqrtf(ss * 0.015625f - mean2 * mean2 + 1e-5f);
  }
  unsigned h2[8];
  #pragma unroll
  for (int mi = 0; mi < 4; ++mi) {
    float o0 = (x2[mi][0] - mean2) * rstd2 * lw2[mi][0] + lb2[mi][0];
    float o1 = (x2[mi][1] - mean2) * rstd2 * lw2[mi][1] + lb2[mi][1];
    float o2 = (x2[mi][2] - mean2) * rstd2 * lw2[mi][2] + lb2[mi][2];
    float o3 = (x2[mi][3] - mean2) * rstd2 * lw2[mi][3] + lb2[mi][3];
    h2[2 * mi] = pk2(o0, o1); h2[2 * mi + 1] = pk2(o2, o3);
  }
  bf16x8 hc0 = frag((u32x4){h2[0], h2[1], h2[2], h2[3]});
  bf16x8 hc1 = frag((u32x4){h2[4], h2[5], h2[6], h2[7]});

  // ---------- FF with rolling 4-frag prefetch groups ----------
  // per chunk c: F1a={32+8c..35+8c} (ml 0,1), F1b={36+8c..39+8c} (ml 2,3)
  //              F2a={64+2c,65+2c,72+2c,73+2c} (mi 0,1), F2b={80+2c,81+2c,88+2c,89+2c}
  f32x4 acc2[4];
  #pragma unroll
  for (int mi = 0; mi < 4; ++mi) acc2[mi] = zf;
  {
    bf16x8 f1a[4], f1b[4], f2a[4], f2b[4];
    #pragma unroll
    for (int i = 0; i < 4; ++i) f1a[i] = ldw(wsm, 32 + i, lane);   // c=0 ml 0,1
    #pragma unroll
    for (int c = 0; c < 4; ++c) {
      #pragma unroll
      for (int i = 0; i < 4; ++i) f1b[i] = ldw(wsm, 36 + 8 * c + i, lane);
      unsigned fr[8];
      #pragma unroll
      for (int ml = 0; ml < 2; ++ml) {   // fc1 ml=0,1 from f1a
        int T = 4 * c + ml;
        f32x4 acc = MFMA16(f1a[2 * ml], hc0, zf); acc = MFMA16(f1a[2 * ml + 1], hc1, acc);
        f32x4 bb = *(const f32x4*)(fc1b + 16 * T + 4 * g);
        fr[2 * ml]     = pk2(fmaxf(acc[0] + bb[0], 0.f), fmaxf(acc[1] + bb[1], 0.f));
        fr[2 * ml + 1] = pk2(fmaxf(acc[2] + bb[2], 0.f), fmaxf(acc[3] + bb[3], 0.f));
      }
      f2a[0] = ldw(wsm, 64 + 2 * c, lane); f2a[1] = ldw(wsm, 65 + 2 * c, lane);
      f2a[2] = ldw(wsm, 72 + 2 * c, lane); f2a[3] = ldw(wsm, 73 + 2 * c, lane);
      #pragma unroll
      for (int ml = 2; ml < 4; ++ml) {   // fc1 ml=2,3 from f1b
        int T = 4 * c + ml;
        f32x4 acc = MFMA16(f1b[2 * (ml - 2)], hc0, zf);
        acc = MFMA16(f1b[2 * (ml - 2) + 1], hc1, acc);
        f32x4 bb = *(const f32x4*)(fc1b + 16 * T + 4 * g);
        fr[2 * ml]     = pk2(fmaxf(acc[0] + bb[0], 0.f), fmaxf(acc[1] + bb[1], 0.f));
        fr[2 * ml + 1] = pk2(fmaxf(acc[2] + bb[2], 0.f), fmaxf(acc[3] + bb[3], 0.f));
      }
      f2b[0] = ldw(wsm, 80 + 2 * c, lane); f2b[1] = ldw(wsm, 81 + 2 * c, lane);
      f2b[2] = ldw(wsm, 88 + 2 * c, lane); f2b[3] = ldw(wsm, 89 + 2 * c, lane);
      bf16x8 bf0 = frag((u32x4){fr[0], fr[1], fr[2], fr[3]});
      bf16x8 bf1 = frag((u32x4){fr[4], fr[5], fr[6], fr[7]});
      acc2[0] = MFMA16(f2a[0], bf0, acc2[0]); acc2[0] = MFMA16(f2a[1], bf1, acc2[0]);
      acc2[1] = MFMA16(f2a[2], bf0, acc2[1]); acc2[1] = MFMA16(f2a[3], bf1, acc2[1]);
      if (c < 3) {
        #pragma unroll
        for (int i = 0; i < 4; ++i) f1a[i] = ldw(wsm, 40 + 8 * c + i, lane);  // next c ml 0,1
      }
      acc2[2] = MFMA16(f2b[0], bf0, acc2[2]); acc2[2] = MFMA16(f2b[1], bf1, acc2[2]);
      acc2[3] = MFMA16(f2b[2], bf0, acc2[3]); acc2[3] = MFMA16(f2b[3], bf1, acc2[3]);
    }
  }

  // ---------- epilogue ----------
  {
    float* ob = out + b * 4096 + myrow * 64;
    #pragma unroll
    for (int mi = 0; mi < 4; ++mi) {
      f32x4 fb = *(const f32x4*)(fc2b + 16 * mi + 4 * g);
      f32x4 o = x2[mi] + acc2[mi] + fb;
      *(f32x4*)(ob + 16 * mi + 4 * g) = o;
    }
  }
}

extern "C" void kernel_launch(void* const* d_in, const int* in_sizes, int n_in,
                              void* d_out, int out_size, void* d_ws, size_t ws_size,
                              hipStream_t stream) {
  const float* x     = (const float*)d_in[0];
  const float* ln1w  = (const float*)d_in[1];
  const float* ln1b  = (const float*)d_in[2];
  const float* wq    = (const float*)d_in[3];
  const float* wk    = (const float*)d_in[4];
  const float* wvp   = (const float*)d_in[5];
  const float* projw = (const float*)d_in[6];
  const float* projb = (const float*)d_in[7];
  const float* ln2w  = (const float*)d_in[8];
  const float* ln2b  = (const float*)d_in[9];
  const float* fc1w  = (const float*)d_in[10];
  const float* fc1b  = (const float*)d_in[11];
  const float* fc2w  = (const float*)d_in[12];
  const float* fc2b  = (const float*)d_in[13];
  unsigned short* ws = (unsigned short*)d_ws;   // 96 KB repacked weights
  float* out = (float*)d_out;

  prep_weights<<<dim3(96), dim3(64), 0, stream>>>(wq, wk, wvp, projw, fc1w, fc2w, ws);

  int nblk = in_sizes[0] / 4096;
  block_fused<<<dim3(nblk), dim3(256), 0, stream>>>(
      x, ln1w, ln1b, projb, ln2w, ln2b, fc1b, fc2b, ws, out);
}